// Round 1
// baseline (392.873 us; speedup 1.0000x reference)
//
#include <hip/hip_runtime.h>
#include <hip/hip_bf16.h>

#define B_ 4
#define T_ 2048
#define HS_ 1024
#define H_ 16
#define R_ 16
#define D_ 64
#define BT_ (B_*T_)          // 8192
#define NC_ 3328             // q(1024) k(1024) v(1024) g(256)
#define CHUNK_ 128
#define NCHUNK_ (T_/CHUNK_)  // 16

typedef __attribute__((ext_vector_type(8))) short short8;
typedef __attribute__((ext_vector_type(4))) float f32x4;

__device__ __forceinline__ float b2f(ushort u){
    union{unsigned int i; float f;} v; v.i = ((unsigned int)u) << 16; return v.f;
}
__device__ __forceinline__ ushort f2b(float f){
    __hip_bfloat16 h = __float2bfloat16(f);
    return *reinterpret_cast<ushort*>(&h);
}
__device__ __forceinline__ float sigm(float x){ return 1.f/(1.f+expf(-x)); }

// ---------- prep kernels ----------
__global__ void k_cast4(const float* __restrict__ src, ushort* __restrict__ dst){
    int i = blockIdx.x*256 + threadIdx.x;
    float4 v = ((const float4*)src)[i];
    ushort4 o; o.x=f2b(v.x); o.y=f2b(v.y); o.z=f2b(v.z); o.w=f2b(v.w);
    ((ushort4*)dst)[i] = o;
}

__global__ void k_build_wcat(const float* __restrict__ qw, const float* __restrict__ kw,
                             const float* __restrict__ vw, const float* __restrict__ gw,
                             ushort* __restrict__ wcat){
    int i = blockIdx.x*256 + threadIdx.x;   // float4 index, total 851968
    int e = i*4;
    int row = e >> 10, col = e & 1023;
    const float* src;
    if      (row < 1024) src = qw + (size_t)row*1024 + col;
    else if (row < 2048) src = kw + (size_t)(row-1024)*1024 + col;
    else if (row < 3072) src = vw + (size_t)(row-2048)*1024 + col;
    else                 src = gw + (size_t)(row-3072)*1024 + col;
    float4 v = *(const float4*)src;
    ushort4 o; o.x=f2b(v.x); o.y=f2b(v.y); o.z=f2b(v.z); o.w=f2b(v.w);
    ((ushort4*)wcat)[i] = o;
}

__global__ void k_rope_tab(float* __restrict__ cosT, float* __restrict__ sinT){
    int i = blockIdx.x*256 + threadIdx.x;   // 65536 = 2048*32
    int t = i >> 5, f = i & 31;
    float inv = powf(10000.f, -(float)f/32.f);
    float a = (float)t * inv;
    cosT[i] = cosf(a);
    sinT[i] = sinf(a);
}

// ---------- bf16 BT-GEMM: C[M][ldc](bf16) = A[M][K](bf16) @ B[N][K]^T ----------
// tile 128x128, BK=32, 4 waves (2x2), each wave 64x64 via 4x4 16x16x32 MFMA
__global__ __launch_bounds__(256) void k_gemm_bt(const ushort* __restrict__ A,
                                                 const ushort* __restrict__ Bm,
                                                 ushort* __restrict__ C,
                                                 int K, int ldc){
    __shared__ __align__(16) ushort Asl[128*40];
    __shared__ __align__(16) ushort Bsl[128*40];
    int tid  = threadIdx.x;
    int lane = tid & 63, wid = tid >> 6;
    int wrow = (wid >> 1)*64, wcol = (wid & 1)*64;
    long arow0 = (long)blockIdx.x * 128;
    long brow0 = (long)blockIdx.y * 128;
    int r0 = tid >> 2, s0 = tid & 3;   // staging row / 16B-seg

    f32x4 acc[4][4];
#pragma unroll
    for(int m=0;m<4;m++)
#pragma unroll
        for(int n=0;n<4;n++)
            acc[m][n] = (f32x4){0.f,0.f,0.f,0.f};

    const int nk = K >> 5;
    for(int kt=0; kt<nk; ++kt){
        int k0 = kt*32;
        __syncthreads();
        *(short8*)&Asl[ r0      *40 + s0*8] = *(const short8*)(A + (arow0      + r0)*K + k0 + s0*8);
        *(short8*)&Asl[(64+r0)  *40 + s0*8] = *(const short8*)(A + (arow0 + 64 + r0)*K + k0 + s0*8);
        *(short8*)&Bsl[ r0      *40 + s0*8] = *(const short8*)(Bm + (brow0      + r0)*K + k0 + s0*8);
        *(short8*)&Bsl[(64+r0)  *40 + s0*8] = *(const short8*)(Bm + (brow0 + 64 + r0)*K + k0 + s0*8);
        __syncthreads();

        int fr = lane & 15, fg = lane >> 4;
        short8 af[4], bf[4];
#pragma unroll
        for(int m=0;m<4;m++) af[m] = *(const short8*)&Asl[(wrow + m*16 + fr)*40 + fg*8];
#pragma unroll
        for(int n=0;n<4;n++) bf[n] = *(const short8*)&Bsl[(wcol + n*16 + fr)*40 + fg*8];
#pragma unroll
        for(int m=0;m<4;m++)
#pragma unroll
            for(int n=0;n<4;n++)
                acc[m][n] = __builtin_amdgcn_mfma_f32_16x16x32_bf16(af[m], bf[n], acc[m][n], 0,0,0);
    }

    int fr = lane & 15, fg = lane >> 4;
#pragma unroll
    for(int m=0;m<4;m++)
#pragma unroll
        for(int n=0;n<4;n++){
            long col = brow0 + wcol + n*16 + fr;
#pragma unroll
            for(int j=0;j<4;j++){
                long row = arow0 + wrow + m*16 + fg*4 + j;
                C[row*(long)ldc + col] = f2b(acc[m][n][j]);
            }
        }
}

// ---------- RoPE + rank projection + gate ----------
// one wave per (b,t,h): rope q,k; q_r = qrope @ Wq[h]^T ; gk = sigmoid(glogit+gb)*k_r*scale
__global__ __launch_bounds__(256) void k_rope_proj(const ushort* __restrict__ qkvg,
                                                   const float* __restrict__ cosT,
                                                   const float* __restrict__ sinT,
                                                   const float* __restrict__ Wq,
                                                   const float* __restrict__ Wk,
                                                   const float* __restrict__ gb,
                                                   float* __restrict__ qr_s,
                                                   float* __restrict__ gk_s){
    __shared__ float lq[4][64], lk[4][64];
    int tid = threadIdx.x, wid = tid >> 6, lane = tid & 63;
    int wg = blockIdx.x*4 + wid;          // 0..131071
    int h  = wg & 15;
    int bt = wg >> 4;                     // b*2048 + t
    int t  = bt & 2047;

    const ushort* qp = qkvg + (size_t)bt*NC_ + h*64;
    float q = b2f(qp[lane]);
    float k = b2f(qp[1024 + lane]);
    int   fi = lane >> 1;
    float c = cosT[t*32 + fi], s = sinT[t*32 + fi];
    float qq = __shfl_xor(q, 1, 64);
    float kk = __shfl_xor(k, 1, 64);
    float qr_, kr_;
    if((lane & 1) == 0){ qr_ = q*c - qq*s;  kr_ = k*c - kk*s; }
    else               { qr_ = qq*s + q*c;  kr_ = kk*s + k*c; }
    lq[wid][lane] = qr_;  lk[wid][lane] = kr_;
    __syncthreads();

    int r = lane & 15, cg = lane >> 4;
    const float* wqp = Wq + ((size_t)(h*16 + r))*64 + cg*16;
    const float* wkp = Wk + ((size_t)(h*16 + r))*64 + cg*16;
    float pq = 0.f, pk = 0.f;
#pragma unroll
    for(int j=0;j<16;j++){
        pq += lq[wid][cg*16 + j] * wqp[j];
        pk += lk[wid][cg*16 + j] * wkp[j];
    }
    pq += __shfl_xor(pq, 16, 64);  pq += __shfl_xor(pq, 32, 64);
    pk += __shfl_xor(pk, 16, 64);  pk += __shfl_xor(pk, 32, 64);

    if(lane < 16){
        int b = bt >> 11;
        size_t o = (((size_t)(b*16 + h))*2048 + t)*16 + r;
        qr_s[o] = pq;
        float gl = b2f(qkvg[(size_t)bt*NC_ + 3072 + h*16 + r]) + gb[h*16 + r];
        gk_s[o] = sigm(gl) * pk * 0.125f;   // scale = 1/sqrt(64)
    }
}

// ---------- scan pass 1: per-chunk local state (M starts at 0) ----------
__global__ __launch_bounds__(64) void k_scan_local(const ushort* __restrict__ qkvg,
                                                   const float* __restrict__ gk_s,
                                                   const float* __restrict__ bdl,
                                                   float* __restrict__ Mloc){
    int lane = threadIdx.x;
    int bx = blockIdx.x;                // bh*16 + chunk
    int ch = bx & 15, bh = bx >> 4;
    int b = bh >> 4, h = bh & 15;
    float dec[16], M[16];
#pragma unroll
    for(int r=0;r<16;r++){ dec[r] = sigm(bdl[h*16+r]); M[r] = 0.f; }

    int t0 = ch*CHUNK_;
    const float4*  gk4 = (const float4*)(gk_s + (((size_t)bh)*2048 + t0)*16);
    const ushort*  vp  = qkvg + ((size_t)(b*2048 + t0))*NC_ + 2048 + h*64 + lane;
    for(int tt=0; tt<CHUNK_; ++tt){
        float v = b2f(*vp); vp += NC_;
        float4 a0 = gk4[0], a1 = gk4[1], a2 = gk4[2], a3 = gk4[3]; gk4 += 4;
        float gk[16] = {a0.x,a0.y,a0.z,a0.w, a1.x,a1.y,a1.z,a1.w,
                        a2.x,a2.y,a2.z,a2.w, a3.x,a3.y,a3.z,a3.w};
#pragma unroll
        for(int r=0;r<16;r++) M[r] = fmaf(M[r], dec[r], gk[r]*v);
    }
    float* mp = Mloc + ((size_t)bx)*1024 + lane;
#pragma unroll
    for(int r=0;r<16;r++) mp[r*64] = M[r];
}

// ---------- scan pass 2: carry combine across chunks ----------
__global__ __launch_bounds__(64) void k_scan_carry(const float* __restrict__ Mloc,
                                                   const float* __restrict__ bdl,
                                                   float* __restrict__ Scar){
    int lane = threadIdx.x, bh = blockIdx.x, h = bh & 15;
    float decC[16], S[16];
#pragma unroll
    for(int r=0;r<16;r++){
        decC[r] = powf(sigm(bdl[h*16+r]), (float)CHUNK_);
        S[r] = 0.f;
    }
    for(int c=0;c<NCHUNK_;c++){
        float*       sp = Scar + ((size_t)(bh*16 + c))*1024 + lane;
        const float* mp = Mloc + ((size_t)(bh*16 + c))*1024 + lane;
#pragma unroll
        for(int r=0;r<16;r++){
            sp[r*64] = S[r];
            S[r] = fmaf(S[r], decC[r], 0.f) + mp[r*64];
        }
    }
}

// ---------- scan pass 3: replay with carried state, emit y ----------
__global__ __launch_bounds__(64) void k_scan_out(const ushort* __restrict__ qkvg,
                                                 const float* __restrict__ gk_s,
                                                 const float* __restrict__ qr_s,
                                                 const float* __restrict__ Scar,
                                                 const float* __restrict__ bdl,
                                                 ushort* __restrict__ Ybf){
    int lane = threadIdx.x;
    int bx = blockIdx.x;
    int ch = bx & 15, bh = bx >> 4;
    int b = bh >> 4, h = bh & 15;
    float dec[16], M[16];
#pragma unroll
    for(int r=0;r<16;r++) dec[r] = sigm(bdl[h*16+r]);
    const float* sp = Scar + ((size_t)bx)*1024 + lane;
#pragma unroll
    for(int r=0;r<16;r++) M[r] = sp[r*64];

    int t0 = ch*CHUNK_;
    const float4* gk4 = (const float4*)(gk_s + (((size_t)bh)*2048 + t0)*16);
    const float4* q4  = (const float4*)(qr_s + (((size_t)bh)*2048 + t0)*16);
    const ushort* vp  = qkvg + ((size_t)(b*2048 + t0))*NC_ + 2048 + h*64 + lane;
    ushort*       yp  = Ybf  + ((size_t)(b*2048 + t0))*1024 + h*64 + lane;
    for(int tt=0; tt<CHUNK_; ++tt){
        float v = b2f(*vp); vp += NC_;
        float4 a0 = gk4[0], a1 = gk4[1], a2 = gk4[2], a3 = gk4[3]; gk4 += 4;
        float4 b0 = q4[0],  b1 = q4[1],  b2 = q4[2],  b3 = q4[3];  q4  += 4;
        float gk[16] = {a0.x,a0.y,a0.z,a0.w, a1.x,a1.y,a1.z,a1.w,
                        a2.x,a2.y,a2.z,a2.w, a3.x,a3.y,a3.z,a3.w};
        float qv[16] = {b0.x,b0.y,b0.z,b0.w, b1.x,b1.y,b1.z,b1.w,
                        b2.x,b2.y,b2.z,b2.w, b3.x,b3.y,b3.z,b3.w};
        float y = 0.f;
#pragma unroll
        for(int r=0;r<16;r++){
            M[r] = fmaf(M[r], dec[r], gk[r]*v);
            y    = fmaf(qv[r], M[r], y);
        }
        *yp = f2b(y); yp += 1024;
    }
}

// ---------- residual + LayerNorm ----------
__global__ __launch_bounds__(256) void k_ln(const float* __restrict__ x,
                                            const ushort* __restrict__ O,
                                            const float* __restrict__ ob,
                                            const float* __restrict__ lg,
                                            const float* __restrict__ lb,
                                            float* __restrict__ out){
    __shared__ float red[8];
    int row = blockIdx.x, tid = threadIdx.x;
    float hv[4];
    float sum = 0.f, ssq = 0.f;
#pragma unroll
    for(int k2=0;k2<4;k2++){
        int j = tid + k2*256;
        float v = x[(size_t)row*1024 + j] + b2f(O[(size_t)row*1024 + j]) + ob[j];
        hv[k2] = v; sum += v; ssq += v*v;
    }
#pragma unroll
    for(int off=32; off; off >>= 1){
        sum += __shfl_down(sum, off, 64);
        ssq += __shfl_down(ssq, off, 64);
    }
    int wid = tid >> 6, lane = tid & 63;
    if(lane == 0){ red[wid] = sum; red[4+wid] = ssq; }
    __syncthreads();
    if(tid == 0){
        float s = red[0]+red[1]+red[2]+red[3];
        float q = red[4]+red[5]+red[6]+red[7];
        float mu = s / 1024.f;
        red[0] = mu;
        red[1] = q / 1024.f - mu*mu;
    }
    __syncthreads();
    float mu = red[0];
    float inv = rsqrtf(red[1] + 1e-5f);
#pragma unroll
    for(int k2=0;k2<4;k2++){
        int j = tid + k2*256;
        out[(size_t)row*1024 + j] = (hv[k2]-mu)*inv*lg[j] + lb[j];
    }
}

extern "C" void kernel_launch(void* const* d_in, const int* in_sizes, int n_in,
                              void* d_out, int out_size, void* d_ws, size_t ws_size,
                              hipStream_t stream){
    const float* x    = (const float*)d_in[0];
    const float* q_w  = (const float*)d_in[1];
    const float* k_w  = (const float*)d_in[2];
    const float* v_w  = (const float*)d_in[3];
    const float* Wq   = (const float*)d_in[4];
    const float* Wk   = (const float*)d_in[5];
    const float* g_w  = (const float*)d_in[6];
    const float* g_b  = (const float*)d_in[7];
    const float* bdl  = (const float*)d_in[8];
    const float* outw = (const float*)d_in[9];
    const float* outb = (const float*)d_in[10];
    const float* ln_g = (const float*)d_in[11];
    const float* ln_b = (const float*)d_in[12];
    float* out = (float*)d_out;

    char* ws = (char*)d_ws;
    size_t off = 0;
    ushort* xbf  = (ushort*)(ws + off); off += (size_t)BT_*HS_*2;        // 16.8MB
    ushort* wcat = (ushort*)(ws + off); off += (size_t)NC_*HS_*2;        // 6.8MB
    ushort* owbf = (ushort*)(ws + off); off += (size_t)HS_*HS_*2;        // 2.1MB
    float*  cosT = (float*)(ws + off);  off += (size_t)T_*32*4;
    float*  sinT = (float*)(ws + off);  off += (size_t)T_*32*4;
    ushort* qkvg = (ushort*)(ws + off); off += (size_t)BT_*NC_*2;        // 54.5MB
    float*  qr_s = (float*)(ws + off);  off += (size_t)BT_*H_*R_/ (size_t)1 *4 / 1; // see below
    // (qr_s size = B*H*T*R floats = 8192*16*16? no: 4*16*2048*16 = 2,097,152)
    // off already advanced by BT_*H_*R_*4 = 8192*256*4 = 8,388,608 bytes. correct.
    float*  gk_s = (float*)(ws + off);  off += (size_t)BT_*H_*R_*4;      // 8.4MB
    float*  Mloc = (float*)(ws + off);  off += (size_t)B_*H_*NCHUNK_*R_*D_*4; // 4MB
    float*  Scar = (float*)(ws + off);  off += (size_t)B_*H_*NCHUNK_*R_*D_*4; // 4MB
    // aliases (safe by dataflow ordering):
    ushort* Ybf = xbf;     // xbf dead after GEMM1
    ushort* O   = qkvg;    // qkvg dead after scan pass 3

    // prep
    k_cast4<<<(BT_*HS_/4)/256, 256, 0, stream>>>(x, xbf);
    k_build_wcat<<<(NC_*HS_/4)/256, 256, 0, stream>>>(q_w, k_w, v_w, g_w, wcat);
    k_cast4<<<(HS_*HS_/4)/256, 256, 0, stream>>>(outw, owbf);
    k_rope_tab<<<(T_*32)/256, 256, 0, stream>>>(cosT, sinT);

    // GEMM1: qkvg[8192][3328] = xbf @ wcat^T
    k_gemm_bt<<<dim3(BT_/128, NC_/128), 256, 0, stream>>>(xbf, wcat, qkvg, HS_, NC_);

    // rope + rank-proj + gate
    k_rope_proj<<<(BT_*H_)/4, 256, 0, stream>>>(qkvg, cosT, sinT, Wq, Wk, g_b, qr_s, gk_s);

    // chunked scan
    k_scan_local<<<B_*H_*NCHUNK_, 64, 0, stream>>>(qkvg, gk_s, bdl, Mloc);
    k_scan_carry<<<B_*H_, 64, 0, stream>>>(Mloc, bdl, Scar);
    k_scan_out<<<B_*H_*NCHUNK_, 64, 0, stream>>>(qkvg, gk_s, qr_s, Scar, bdl, Ybf);

    // GEMM2: O[8192][1024] = Ybf @ owbf^T  (O aliases qkvg region)
    k_gemm_bt<<<dim3(BT_/128, HS_/128), 256, 0, stream>>>(Ybf, owbf, O, HS_, HS_);

    // residual + LayerNorm
    k_ln<<<BT_, 256, 0, stream>>>(x, O, outb, ln_g, ln_b, out);

    (void)in_sizes; (void)n_in; (void)out_size; (void)ws_size;
}

// Round 2
// 222.382 us; speedup vs baseline: 1.7667x; 1.7667x over previous
//
#include <hip/hip_runtime.h>
#include <hip/hip_bf16.h>

#define B_ 4
#define T_ 2048
#define HS_ 1024
#define H_ 16
#define R_ 16
#define D_ 64
#define BT_ (B_*T_)          // 8192
#define NC_ 3328             // q(1024) k(1024) v(1024) g(256)
#define CHUNK_ 64
#define NCHUNK_ (T_/CHUNK_)  // 32

typedef __attribute__((ext_vector_type(8))) short short8;
typedef __attribute__((ext_vector_type(4))) float f32x4;

__device__ __forceinline__ float b2f(ushort u){
    union{unsigned int i; float f;} v; v.i = ((unsigned int)u) << 16; return v.f;
}
__device__ __forceinline__ ushort f2b(float f){
    __hip_bfloat16 h = __float2bfloat16(f);
    return *reinterpret_cast<ushort*>(&h);
}
__device__ __forceinline__ float sigm(float x){ return 1.f/(1.f+expf(-x)); }

// async global->LDS, 16B per lane; lds dest is wave-uniform base + lane*16
__device__ __forceinline__ void gl_lds16(const void* g, void* l){
    __builtin_amdgcn_global_load_lds((const __attribute__((address_space(1))) void*)g,
                                     (__attribute__((address_space(3))) void*)l,
                                     16, 0, 0);
}

// ---------- prep kernels ----------
__global__ void k_cast4(const float* __restrict__ src, ushort* __restrict__ dst){
    int i = blockIdx.x*256 + threadIdx.x;
    float4 v = ((const float4*)src)[i];
    ushort4 o; o.x=f2b(v.x); o.y=f2b(v.y); o.z=f2b(v.z); o.w=f2b(v.w);
    ((ushort4*)dst)[i] = o;
}

__global__ void k_build_wcat(const float* __restrict__ qw, const float* __restrict__ kw,
                             const float* __restrict__ vw, const float* __restrict__ gw,
                             ushort* __restrict__ wcat){
    int i = blockIdx.x*256 + threadIdx.x;   // float4 index
    int e = i*4;
    int row = e >> 10, col = e & 1023;
    const float* src;
    if      (row < 1024) src = qw + (size_t)row*1024 + col;
    else if (row < 2048) src = kw + (size_t)(row-1024)*1024 + col;
    else if (row < 3072) src = vw + (size_t)(row-2048)*1024 + col;
    else                 src = gw + (size_t)(row-3072)*1024 + col;
    float4 v = *(const float4*)src;
    ushort4 o; o.x=f2b(v.x); o.y=f2b(v.y); o.z=f2b(v.z); o.w=f2b(v.w);
    ((ushort4*)wcat)[i] = o;
}

__global__ void k_rope_tab(float* __restrict__ cosT, float* __restrict__ sinT){
    int i = blockIdx.x*256 + threadIdx.x;   // 65536 = 2048*32
    int t = i >> 5, f = i & 31;
    float inv = powf(10000.f, -(float)f/32.f);
    float a = (float)t * inv;
    cosT[i] = cosf(a);
    sinT[i] = sinf(a);
}

// ---------- bf16 BT-GEMM (m97 structure): C[M][ldc](bf16) = A[M][K] @ B[N][K]^T ----------
// 128x128 tile, BK=32, 4 waves (2x2), linear LDS + global_load_lds dwordx4
__global__ __launch_bounds__(256) void k_gemm_bt(const ushort* __restrict__ A,
                                                 const ushort* __restrict__ Bm,
                                                 ushort* __restrict__ C,
                                                 int K, int ldc){
    __shared__ __align__(16) ushort Asl[128*32];
    __shared__ __align__(16) ushort Bsl[128*32];
    int tid  = threadIdx.x;
    int lane = tid & 63, wid = tid >> 6;
    int wrow = (wid >> 1)*64, wcol = (wid & 1)*64;
    long arow0 = (long)blockIdx.x * 128;
    long brow0 = (long)blockIdx.y * 128;

    // staging: thread t covers tile row t/4, 16B-seg t%4 (linear LDS = t*16B)
    int srow = tid >> 2, sseg = (tid & 3)*8;
    const ushort* ga0 = A  + (arow0      + srow)*(size_t)K + sseg;
    const ushort* ga1 = ga0 + 64*(size_t)K;
    const ushort* gb0 = Bm + (brow0      + srow)*(size_t)K + sseg;
    const ushort* gb1 = gb0 + 64*(size_t)K;
    ushort* la0 = &Asl[(tid>>6)*512];   // wave-uniform LDS base (1KB/wave)
    ushort* la1 = la0 + 2048;
    ushort* lb0 = &Bsl[(tid>>6)*512];
    ushort* lb1 = lb0 + 2048;

    f32x4 acc[4][4];
#pragma unroll
    for(int m=0;m<4;m++)
#pragma unroll
        for(int n=0;n<4;n++)
            acc[m][n] = (f32x4){0.f,0.f,0.f,0.f};

    int fr = lane & 15, fg = lane >> 4;
    for(int kt=0; kt<K; kt+=32){
        __syncthreads();
        gl_lds16(ga0 + kt, la0);
        gl_lds16(ga1 + kt, la1);
        gl_lds16(gb0 + kt, lb0);
        gl_lds16(gb1 + kt, lb1);
        __syncthreads();   // drains vmcnt -> LDS tiles ready

        short8 af[4], bfr[4];
#pragma unroll
        for(int m=0;m<4;m++) af[m]  = *(const short8*)&Asl[(wrow + m*16 + fr)*32 + fg*8];
#pragma unroll
        for(int n=0;n<4;n++) bfr[n] = *(const short8*)&Bsl[(wcol + n*16 + fr)*32 + fg*8];
#pragma unroll
        for(int m=0;m<4;m++)
#pragma unroll
            for(int n=0;n<4;n++)
                acc[m][n] = __builtin_amdgcn_mfma_f32_16x16x32_bf16(af[m], bfr[n], acc[m][n], 0,0,0);
    }

#pragma unroll
    for(int m=0;m<4;m++)
#pragma unroll
        for(int n=0;n<4;n++){
            long col = brow0 + wcol + n*16 + fr;
#pragma unroll
            for(int j=0;j<4;j++){
                long row = arow0 + wrow + m*16 + fg*4 + j;
                C[row*(long)ldc + col] = f2b(acc[m][n][j]);
            }
        }
}

// ---------- RoPE + rank projection + gate (MFMA version) ----------
// grid (BT/64, H), 256 threads. Rope q,k in-register during staging,
// then per-wave 16x16 MFMA projections against Wq/Wk[h], fused gate epilogue.
__global__ __launch_bounds__(256) void k_rope_proj(const ushort* __restrict__ qkvg,
                                                   const float* __restrict__ cosT,
                                                   const float* __restrict__ sinT,
                                                   const float* __restrict__ Wq,
                                                   const float* __restrict__ Wk,
                                                   const float* __restrict__ gb,
                                                   float* __restrict__ qr_s,
                                                   float* __restrict__ gk_s){
    __shared__ __align__(16) ushort lq[64*72], lk[64*72];
    __shared__ __align__(16) ushort wql[16*72], wkl[16*72];
    int tid = threadIdx.x, wid = tid >> 6, lane = tid & 63;
    int bt0 = blockIdx.x * 64;
    int h   = blockIdx.y;

    // stage Wq/Wk[h] -> bf16 LDS  (16 rows x 16 float4-segs = 256 loads each)
    {
        int row = tid >> 4, seg = tid & 15;
        float4 wq4 = *(const float4*)(Wq + (size_t)h*1024 + row*64 + seg*4);
        float4 wk4 = *(const float4*)(Wk + (size_t)h*1024 + row*64 + seg*4);
        ushort* dq = &wql[row*72 + seg*4];
        ushort* dk = &wkl[row*72 + seg*4];
        dq[0]=f2b(wq4.x); dq[1]=f2b(wq4.y); dq[2]=f2b(wq4.z); dq[3]=f2b(wq4.w);
        dk[0]=f2b(wk4.x); dk[1]=f2b(wk4.y); dk[2]=f2b(wk4.z); dk[3]=f2b(wk4.w);
    }

    // stage q,k with rope applied (2 reps x 256 threads = 64 rows x 8 segs)
#pragma unroll
    for(int rep=0; rep<2; ++rep){
        int flat = rep*256 + tid;
        int row = flat >> 3, seg = flat & 7;
        int t = (bt0 + row) & 2047;
        const ushort* base = qkvg + (size_t)(bt0+row)*NC_ + h*64 + seg*8;
        short8 q8 = *(const short8*)base;
        short8 k8 = *(const short8*)(base + 1024);
        float4 cv = *(const float4*)&cosT[t*32 + seg*4];
        float4 sv = *(const float4*)&sinT[t*32 + seg*4];
        float qf[8], kf[8];
#pragma unroll
        for(int j=0;j<8;j++){ qf[j]=b2f((ushort)q8[j]); kf[j]=b2f((ushort)k8[j]); }
        float c4[4] = {cv.x,cv.y,cv.z,cv.w};
        float s4[4] = {sv.x,sv.y,sv.z,sv.w};
        short8 qo, ko;
#pragma unroll
        for(int p=0;p<4;p++){
            float c=c4[p], s=s4[p];
            qo[2*p]   = (short)f2b(qf[2*p]*c - qf[2*p+1]*s);
            qo[2*p+1] = (short)f2b(qf[2*p]*s + qf[2*p+1]*c);
            ko[2*p]   = (short)f2b(kf[2*p]*c - kf[2*p+1]*s);
            ko[2*p+1] = (short)f2b(kf[2*p]*s + kf[2*p+1]*c);
        }
        *(short8*)&lq[row*72 + seg*8] = qo;
        *(short8*)&lk[row*72 + seg*8] = ko;
    }
    __syncthreads();

    // MFMA: wave w does rows w*16..w*16+15; K=64 -> 2 mfma per projection
    int fr = lane & 15, fg = lane >> 4;
    int wrow = wid*16;
    short8 aq0 = *(const short8*)&lq[(wrow+fr)*72 + fg*8];
    short8 aq1 = *(const short8*)&lq[(wrow+fr)*72 + 32 + fg*8];
    short8 ak0 = *(const short8*)&lk[(wrow+fr)*72 + fg*8];
    short8 ak1 = *(const short8*)&lk[(wrow+fr)*72 + 32 + fg*8];
    short8 bq0 = *(const short8*)&wql[fr*72 + fg*8];
    short8 bq1 = *(const short8*)&wql[fr*72 + 32 + fg*8];
    short8 bk0 = *(const short8*)&wkl[fr*72 + fg*8];
    short8 bk1 = *(const short8*)&wkl[fr*72 + 32 + fg*8];
    f32x4 accq = (f32x4){0.f,0.f,0.f,0.f};
    f32x4 acck = (f32x4){0.f,0.f,0.f,0.f};
    accq = __builtin_amdgcn_mfma_f32_16x16x32_bf16(aq0, bq0, accq, 0,0,0);
    accq = __builtin_amdgcn_mfma_f32_16x16x32_bf16(aq1, bq1, accq, 0,0,0);
    acck = __builtin_amdgcn_mfma_f32_16x16x32_bf16(ak0, bk0, acck, 0,0,0);
    acck = __builtin_amdgcn_mfma_f32_16x16x32_bf16(ak1, bk1, acck, 0,0,0);

    // C layout: col(=r) = lane&15, row = (lane>>4)*4 + j
    int r = fr;
    float gbv = gb[h*16 + r];
#pragma unroll
    for(int j=0;j<4;j++){
        int bt = bt0 + wrow + fg*4 + j;
        int t  = bt & 2047, b = bt >> 11;
        size_t o = (((size_t)(b*16 + h))*2048 + t)*16 + r;
        qr_s[o] = accq[j];
        float gl = b2f(qkvg[(size_t)bt*NC_ + 3072 + h*16 + r]) + gbv;
        gk_s[o] = sigm(gl) * acck[j] * 0.125f;   // scale = 1/sqrt(64)
    }
}

// ---------- scan pass 1: per-chunk local state (M starts at 0) ----------
__global__ __launch_bounds__(64) void k_scan_local(const ushort* __restrict__ qkvg,
                                                   const float* __restrict__ gk_s,
                                                   const float* __restrict__ bdl,
                                                   float* __restrict__ Mloc){
    int lane = threadIdx.x;
    int bx = blockIdx.x;                // bh*NCHUNK + chunk
    int ch = bx & (NCHUNK_-1), bh = bx >> 5;
    int b = bh >> 4, h = bh & 15;
    float dec[16], M[16];
#pragma unroll
    for(int r=0;r<16;r++){ dec[r] = sigm(bdl[h*16+r]); M[r] = 0.f; }

    int t0 = ch*CHUNK_;
    const float4*  gk4 = (const float4*)(gk_s + (((size_t)bh)*2048 + t0)*16);
    const ushort*  vp  = qkvg + ((size_t)(b*2048 + t0))*NC_ + 2048 + h*64 + lane;
    for(int tt=0; tt<CHUNK_; ++tt){
        float v = b2f(*vp); vp += NC_;
        float4 a0 = gk4[0], a1 = gk4[1], a2 = gk4[2], a3 = gk4[3]; gk4 += 4;
        float gk[16] = {a0.x,a0.y,a0.z,a0.w, a1.x,a1.y,a1.z,a1.w,
                        a2.x,a2.y,a2.z,a2.w, a3.x,a3.y,a3.z,a3.w};
#pragma unroll
        for(int r=0;r<16;r++) M[r] = fmaf(M[r], dec[r], gk[r]*v);
    }
    float* mp = Mloc + ((size_t)bx)*1024 + lane;
#pragma unroll
    for(int r=0;r<16;r++) mp[r*64] = M[r];
}

// ---------- scan pass 2: carry combine IN-PLACE (Mloc[c] becomes state at chunk start) ----------
__global__ __launch_bounds__(64) void k_scan_carry(float* __restrict__ Mloc,
                                                   const float* __restrict__ bdl){
    int lane = threadIdx.x;
    int sub = blockIdx.x & 3, bh = blockIdx.x >> 2, h = bh & 15;
    float decC[4], S[4];
#pragma unroll
    for(int rr=0;rr<4;rr++){
        decC[rr] = powf(sigm(bdl[h*16 + sub*4 + rr]), (float)CHUNK_);
        S[rr] = 0.f;
    }
    for(int c=0;c<NCHUNK_;c++){
        float* p = Mloc + ((size_t)(bh*NCHUNK_ + c))*1024 + lane + sub*4*64;
#pragma unroll
        for(int rr=0;rr<4;rr++){
            float m = p[rr*64];
            p[rr*64] = S[rr];
            S[rr] = fmaf(S[rr], decC[rr], m);
        }
    }
}

// ---------- scan pass 3: replay with carried state, emit y ----------
__global__ __launch_bounds__(64) void k_scan_out(const ushort* __restrict__ qkvg,
                                                 const float* __restrict__ gk_s,
                                                 const float* __restrict__ qr_s,
                                                 const float* __restrict__ Mst,
                                                 const float* __restrict__ bdl,
                                                 ushort* __restrict__ Ybf){
    int lane = threadIdx.x;
    int bx = blockIdx.x;
    int ch = bx & (NCHUNK_-1), bh = bx >> 5;
    int b = bh >> 4, h = bh & 15;
    float dec[16], M[16];
#pragma unroll
    for(int r=0;r<16;r++) dec[r] = sigm(bdl[h*16+r]);
    const float* sp = Mst + ((size_t)bx)*1024 + lane;
#pragma unroll
    for(int r=0;r<16;r++) M[r] = sp[r*64];

    int t0 = ch*CHUNK_;
    const float4* gk4 = (const float4*)(gk_s + (((size_t)bh)*2048 + t0)*16);
    const float4* q4  = (const float4*)(qr_s + (((size_t)bh)*2048 + t0)*16);
    const ushort* vp  = qkvg + ((size_t)(b*2048 + t0))*NC_ + 2048 + h*64 + lane;
    ushort*       yp  = Ybf  + ((size_t)(b*2048 + t0))*1024 + h*64 + lane;
    for(int tt=0; tt<CHUNK_; ++tt){
        float v = b2f(*vp); vp += NC_;
        float4 a0 = gk4[0], a1 = gk4[1], a2 = gk4[2], a3 = gk4[3]; gk4 += 4;
        float4 b0 = q4[0],  b1 = q4[1],  b2 = q4[2],  b3 = q4[3];  q4  += 4;
        float gk[16] = {a0.x,a0.y,a0.z,a0.w, a1.x,a1.y,a1.z,a1.w,
                        a2.x,a2.y,a2.z,a2.w, a3.x,a3.y,a3.z,a3.w};
        float qv[16] = {b0.x,b0.y,b0.z,b0.w, b1.x,b1.y,b1.z,b1.w,
                        b2.x,b2.y,b2.z,b2.w, b3.x,b3.y,b3.z,b3.w};
        float y = 0.f;
#pragma unroll
        for(int r=0;r<16;r++){
            M[r] = fmaf(M[r], dec[r], gk[r]*v);
            y    = fmaf(qv[r], M[r], y);
        }
        *yp = f2b(y); yp += 1024;
    }
}

// ---------- residual + LayerNorm ----------
__global__ __launch_bounds__(256) void k_ln(const float* __restrict__ x,
                                            const ushort* __restrict__ O,
                                            const float* __restrict__ ob,
                                            const float* __restrict__ lg,
                                            const float* __restrict__ lb,
                                            float* __restrict__ out){
    __shared__ float red[8];
    int row = blockIdx.x, tid = threadIdx.x;
    float hv[4];
    float sum = 0.f, ssq = 0.f;
#pragma unroll
    for(int k2=0;k2<4;k2++){
        int j = tid + k2*256;
        float v = x[(size_t)row*1024 + j] + b2f(O[(size_t)row*1024 + j]) + ob[j];
        hv[k2] = v; sum += v; ssq += v*v;
    }
#pragma unroll
    for(int off=32; off; off >>= 1){
        sum += __shfl_down(sum, off, 64);
        ssq += __shfl_down(ssq, off, 64);
    }
    int wid = tid >> 6, lane = tid & 63;
    if(lane == 0){ red[wid] = sum; red[4+wid] = ssq; }
    __syncthreads();
    if(tid == 0){
        float s = red[0]+red[1]+red[2]+red[3];
        float q = red[4]+red[5]+red[6]+red[7];
        float mu = s / 1024.f;
        red[0] = mu;
        red[1] = q / 1024.f - mu*mu;
    }
    __syncthreads();
    float mu = red[0];
    float inv = rsqrtf(red[1] + 1e-5f);
#pragma unroll
    for(int k2=0;k2<4;k2++){
        int j = tid + k2*256;
        out[(size_t)row*1024 + j] = (hv[k2]-mu)*inv*lg[j] + lb[j];
    }
}

extern "C" void kernel_launch(void* const* d_in, const int* in_sizes, int n_in,
                              void* d_out, int out_size, void* d_ws, size_t ws_size,
                              hipStream_t stream){
    const float* x    = (const float*)d_in[0];
    const float* q_w  = (const float*)d_in[1];
    const float* k_w  = (const float*)d_in[2];
    const float* v_w  = (const float*)d_in[3];
    const float* Wq   = (const float*)d_in[4];
    const float* Wk   = (const float*)d_in[5];
    const float* g_w  = (const float*)d_in[6];
    const float* g_b  = (const float*)d_in[7];
    const float* bdl  = (const float*)d_in[8];
    const float* outw = (const float*)d_in[9];
    const float* outb = (const float*)d_in[10];
    const float* ln_g = (const float*)d_in[11];
    const float* ln_b = (const float*)d_in[12];
    float* out = (float*)d_out;

    char* ws = (char*)d_ws;
    size_t off = 0;
    ushort* xbf  = (ushort*)(ws + off); off += (size_t)BT_*HS_*2;        // 16.8MB
    ushort* wcat = (ushort*)(ws + off); off += (size_t)NC_*HS_*2;        // 6.8MB
    ushort* owbf = (ushort*)(ws + off); off += (size_t)HS_*HS_*2;        // 2.1MB
    float*  cosT = (float*)(ws + off);  off += (size_t)T_*32*4;
    float*  sinT = (float*)(ws + off);  off += (size_t)T_*32*4;
    ushort* qkvg = (ushort*)(ws + off); off += (size_t)BT_*NC_*2;        // 54.5MB
    float*  qr_s = (float*)(ws + off);  off += (size_t)BT_*H_*R_*4;      // 8.4MB
    float*  gk_s = (float*)(ws + off);  off += (size_t)BT_*H_*R_*4;      // 8.4MB
    float*  Mloc = (float*)(ws + off);  off += (size_t)B_*H_*NCHUNK_*R_*D_*4; // 8.4MB
    // aliases (safe by dataflow ordering):
    ushort* Ybf = xbf;     // xbf dead after GEMM1
    ushort* O   = qkvg;    // qkvg dead after scan pass 3

    // prep
    k_cast4<<<(BT_*HS_/4)/256, 256, 0, stream>>>(x, xbf);
    k_build_wcat<<<(NC_*HS_/4)/256, 256, 0, stream>>>(q_w, k_w, v_w, g_w, wcat);
    k_cast4<<<(HS_*HS_/4)/256, 256, 0, stream>>>(outw, owbf);
    k_rope_tab<<<(T_*32)/256, 256, 0, stream>>>(cosT, sinT);

    // GEMM1: qkvg[8192][3328] = xbf @ wcat^T
    k_gemm_bt<<<dim3(BT_/128, NC_/128), 256, 0, stream>>>(xbf, wcat, qkvg, HS_, NC_);

    // rope + rank-proj + gate (MFMA)
    k_rope_proj<<<dim3(BT_/64, H_), 256, 0, stream>>>(qkvg, cosT, sinT, Wq, Wk, g_b, qr_s, gk_s);

    // chunked scan
    k_scan_local<<<B_*H_*NCHUNK_, 64, 0, stream>>>(qkvg, gk_s, bdl, Mloc);
    k_scan_carry<<<B_*H_*4, 64, 0, stream>>>(Mloc, bdl);
    k_scan_out<<<B_*H_*NCHUNK_, 64, 0, stream>>>(qkvg, gk_s, qr_s, Mloc, bdl, Ybf);

    // GEMM2: O[8192][1024] = Ybf @ owbf^T  (O aliases qkvg region)
    k_gemm_bt<<<dim3(BT_/128, HS_/128), 256, 0, stream>>>(Ybf, owbf, O, HS_, HS_);

    // residual + LayerNorm
    k_ln<<<BT_, 256, 0, stream>>>(x, O, outb, ln_g, ln_b, out);

    (void)in_sizes; (void)n_in; (void)out_size; (void)ws_size;
}